// Round 1
// baseline (133.308 us; speedup 1.0000x reference)
//
#include <hip/hip_runtime.h>

// Problem shape (from reference): E=524288, IN=256, OUT=256, T=16
//   y[t] = x_j[t] @ W[t]   (tiny: 16x256x256)
//   out[e] = y[edge_types[e]]   (memory-bound gather, 512 MB fp32 writes)

#define RL_IN  256
#define RL_OUT 256
#define RL_T   16

// ---------------------------------------------------------------------------
// Kernel 1: per-type matvec. block t computes y[t][:]; thread o owns output o.
// W reads are coalesced: for fixed i, W[t][i][o] is contiguous across o.
// ---------------------------------------------------------------------------
__global__ __launch_bounds__(RL_OUT)
void rl_compute_y(const float* __restrict__ x,
                  const float* __restrict__ W,
                  float* __restrict__ y) {
    const int t = blockIdx.x;     // 0..15
    const int o = threadIdx.x;    // 0..255

    __shared__ float xs[RL_IN];
    xs[o] = x[t * RL_IN + o];
    __syncthreads();

    const float* Wt = W + (size_t)t * RL_IN * RL_OUT;
    float acc = 0.0f;
#pragma unroll 8
    for (int i = 0; i < RL_IN; ++i) {
        acc += xs[i] * Wt[i * RL_OUT + o];
    }
    y[t * RL_OUT + o] = acc;
}

// ---------------------------------------------------------------------------
// Kernel 2: gather rows. One wave (64 lanes) per row: 64 x float4 = 1024 B =
// one full row, fully coalesced aligned stores (no fetch-on-write).
// y (16 KB) staged in LDS; edge_types[row] is wave-uniform (broadcast load).
// ---------------------------------------------------------------------------
__global__ __launch_bounds__(256)
void rl_gather(const int* __restrict__ et,
               const float4* __restrict__ y4,   // [T*64] float4
               float4* __restrict__ out4,       // [E*64] float4
               int E) {
    __shared__ float4 ys[RL_T * (RL_OUT / 4)];  // 16 * 64 = 1024 float4 = 16 KB

    for (int i = threadIdx.x; i < RL_T * (RL_OUT / 4); i += blockDim.x)
        ys[i] = y4[i];
    __syncthreads();

    const int lane         = threadIdx.x & 63;
    const int waveInBlock  = threadIdx.x >> 6;
    const int wavesPerBlk  = blockDim.x >> 6;
    const int totalWaves   = gridDim.x * wavesPerBlk;
    int row = blockIdx.x * wavesPerBlk + waveInBlock;

    for (; row < E; row += totalWaves) {
        const int t = et[row];                       // wave-uniform broadcast
        out4[(size_t)row * 64 + lane] = ys[t * 64 + lane];
    }
}

extern "C" void kernel_launch(void* const* d_in, const int* in_sizes, int n_in,
                              void* d_out, int out_size, void* d_ws, size_t ws_size,
                              hipStream_t stream) {
    const float* x_j  = (const float*)d_in[0];   // [E, IN] (only first T rows used)
    const float* W    = (const float*)d_in[1];   // [T, IN, OUT]
    const int*   et   = (const int*)d_in[2];     // [E]
    float*       out  = (float*)d_out;           // [E, OUT]

    const int E = in_sizes[2];                   // 524288

    float* y = (float*)d_ws;                     // [T, OUT] = 16 KB scratch

    rl_compute_y<<<RL_T, RL_OUT, 0, stream>>>(x_j, W, y);

    const int block = 256;
    const int grid  = 2048;                      // 8 blocks/CU, grid-stride
    rl_gather<<<grid, block, 0, stream>>>(et, (const float4*)y,
                                          (float4*)out, E);
}

// Round 2
// 121.454 us; speedup vs baseline: 1.0976x; 1.0976x over previous
//
#include <hip/hip_runtime.h>

// Problem shape: E=524288, IN=256, OUT=256, T=16
//   y[t] = x_j[t] @ W[t]       (tiny compute: 16x256x256, 16 MB of W)
//   out[e] = y[edge_types[e]]  (memory-bound gather: 512 MB fp32 writes)
//
// R1 post-mortem: gather is near write-roofline; the 16-block matvec was a
// ~15-40us latency-bound serial prologue. Split IN into chunks -> 128-block
// partial kernel (coalesced 1KB row reads) + 16-block reduce.

#define RL_IN  256
#define RL_OUT 256
#define RL_T   16
#define RL_NCHUNK 8
#define RL_CHUNK  (RL_IN / RL_NCHUNK)   // 32

// ---------------------------------------------------------------------------
// Kernel A: partial matvec. block (t,c) computes
//   partial[t][c][o] = sum_{i in chunk c} x[t][i] * W[t][i][o]
// Reads 32 contiguous 1KB rows per block, perfectly coalesced. 128 blocks.
// ---------------------------------------------------------------------------
__global__ __launch_bounds__(RL_OUT)
void rl_partial(const float* __restrict__ x,
                const float* __restrict__ W,
                float* __restrict__ partial) {
    const int t = blockIdx.x / RL_NCHUNK;
    const int c = blockIdx.x % RL_NCHUNK;
    const int o = threadIdx.x;            // 0..255
    const int i0 = c * RL_CHUNK;

    __shared__ float xs[RL_CHUNK];
    if (o < RL_CHUNK) xs[o] = x[t * RL_IN + i0 + o];
    __syncthreads();

    const float* Wt = W + (size_t)t * RL_IN * RL_OUT + (size_t)i0 * RL_OUT;
    float acc = 0.0f;
#pragma unroll 8
    for (int i = 0; i < RL_CHUNK; ++i) {
        acc += xs[i] * Wt[i * RL_OUT + o];
    }
    partial[((size_t)t * RL_NCHUNK + c) * RL_OUT + o] = acc;
}

// ---------------------------------------------------------------------------
// Kernel B: reduce partials -> y[t][o]. 16 blocks x 256 threads, reads 128KB.
// ---------------------------------------------------------------------------
__global__ __launch_bounds__(RL_OUT)
void rl_reduce(const float* __restrict__ partial,
               float* __restrict__ y) {
    const int t = blockIdx.x;
    const int o = threadIdx.x;
    float acc = 0.0f;
#pragma unroll
    for (int c = 0; c < RL_NCHUNK; ++c)
        acc += partial[((size_t)t * RL_NCHUNK + c) * RL_OUT + o];
    y[t * RL_OUT + o] = acc;
}

// ---------------------------------------------------------------------------
// Kernel C: gather rows. One wave (64 lanes) per row: 64 x float4 = 1024B =
// one full row, fully coalesced aligned stores. y (16KB) staged in LDS;
// edge_types[row] is wave-uniform (broadcast load).
// ---------------------------------------------------------------------------
__global__ __launch_bounds__(256)
void rl_gather(const int* __restrict__ et,
               const float4* __restrict__ y4,   // [T*64] float4
               float4* __restrict__ out4,       // [E*64] float4
               int E) {
    __shared__ float4 ys[RL_T * (RL_OUT / 4)];  // 1024 float4 = 16 KB

    for (int i = threadIdx.x; i < RL_T * (RL_OUT / 4); i += blockDim.x)
        ys[i] = y4[i];
    __syncthreads();

    const int lane        = threadIdx.x & 63;
    const int waveInBlock = threadIdx.x >> 6;
    const int wavesPerBlk = blockDim.x >> 6;
    const int totalWaves  = gridDim.x * wavesPerBlk;
    int row = blockIdx.x * wavesPerBlk + waveInBlock;

    for (; row < E; row += totalWaves) {
        const int t = et[row];                       // wave-uniform broadcast
        out4[(size_t)row * 64 + lane] = ys[t * 64 + lane];
    }
}

extern "C" void kernel_launch(void* const* d_in, const int* in_sizes, int n_in,
                              void* d_out, int out_size, void* d_ws, size_t ws_size,
                              hipStream_t stream) {
    const float* x_j  = (const float*)d_in[0];   // [E, IN] (first T rows used)
    const float* W    = (const float*)d_in[1];   // [T, IN, OUT]
    const int*   et   = (const int*)d_in[2];     // [E]
    float*       out  = (float*)d_out;           // [E, OUT]

    const int E = in_sizes[2];                   // 524288

    // Workspace layout: partial [T*NCHUNK*OUT] then y [T*OUT]
    float* partial = (float*)d_ws;                           // 128 KB
    float* y       = partial + (size_t)RL_T * RL_NCHUNK * RL_OUT; // 16 KB

    rl_partial<<<RL_T * RL_NCHUNK, RL_OUT, 0, stream>>>(x_j, W, partial);
    rl_reduce<<<RL_T, RL_OUT, 0, stream>>>(partial, y);

    rl_gather<<<2048, 256, 0, stream>>>(et, (const float4*)y,
                                        (float4*)out, E);
}

// Round 4
// 109.556 us; speedup vs baseline: 1.2168x; 1.1086x over previous
//
#include <hip/hip_runtime.h>

// Problem shape: E=524288, IN=256, OUT=256, T=16
//   y[t] = x_j[t] @ W[t]       (tiny compute: 16x256x256, 4 MB of W)
//   out[e] = y[edge_types[e]]  (memory-bound gather: 512 MB fp32 writes)
//
// R3 fix: __builtin_nontemporal_store needs a native vector type, not
// HIP_vector_type. Use ext_vector_type(4) float for the store path.

#define RL_IN  256
#define RL_OUT 256
#define RL_T   16
#define RL_NCHUNK 8
#define RL_CHUNK  (RL_IN / RL_NCHUNK)   // 32

typedef float f32x4 __attribute__((ext_vector_type(4)));

// ---------------------------------------------------------------------------
// Kernel A: partial matvec. block (t,c):
//   partial[t][c][o] = sum_{i in chunk c} x[t][i] * W[t][i][o]
// 128 blocks, coalesced 1KB row reads.
// ---------------------------------------------------------------------------
__global__ __launch_bounds__(RL_OUT)
void rl_partial(const float* __restrict__ x,
                const float* __restrict__ W,
                float* __restrict__ partial) {
    const int t = blockIdx.x / RL_NCHUNK;
    const int c = blockIdx.x % RL_NCHUNK;
    const int o = threadIdx.x;            // 0..255
    const int i0 = c * RL_CHUNK;

    __shared__ float xs[RL_CHUNK];
    if (o < RL_CHUNK) xs[o] = x[t * RL_IN + i0 + o];
    __syncthreads();

    const float* Wt = W + (size_t)t * RL_IN * RL_OUT + (size_t)i0 * RL_OUT;
    float acc = 0.0f;
#pragma unroll 8
    for (int i = 0; i < RL_CHUNK; ++i) {
        acc += xs[i] * Wt[i * RL_OUT + o];
    }
    partial[((size_t)t * RL_NCHUNK + c) * RL_OUT + o] = acc;
}

// ---------------------------------------------------------------------------
// Kernel B: reduce partials -> y[t][o]. 16 blocks x 256 threads.
// ---------------------------------------------------------------------------
__global__ __launch_bounds__(RL_OUT)
void rl_reduce(const float* __restrict__ partial,
               float* __restrict__ y) {
    const int t = blockIdx.x;
    const int o = threadIdx.x;
    float acc = 0.0f;
#pragma unroll
    for (int c = 0; c < RL_NCHUNK; ++c)
        acc += partial[((size_t)t * RL_NCHUNK + c) * RL_OUT + o];
    y[t * RL_OUT + o] = acc;
}

// ---------------------------------------------------------------------------
// Kernel C: gather. One wave handles 4 consecutive rows per iteration:
// one int4 et load (wave-uniform, 1 cache line) -> 4 independent
// (LDS read -> 1KB nontemporal store) pairs. 64 lanes x f32x4 = full row.
// ---------------------------------------------------------------------------
__global__ __launch_bounds__(256)
void rl_gather(const int4* __restrict__ et4,   // [E/4]
               const f32x4* __restrict__ y4,   // [T*64]
               f32x4* __restrict__ out4,       // [E*64]
               int E4) {
    __shared__ f32x4 ys[RL_T * (RL_OUT / 4)];  // 1024 * 16B = 16 KB

    for (int i = threadIdx.x; i < RL_T * (RL_OUT / 4); i += blockDim.x)
        ys[i] = y4[i];
    __syncthreads();

    const int lane       = threadIdx.x & 63;
    const int wave       = blockIdx.x * (blockDim.x >> 6) + (threadIdx.x >> 6);
    const int totalWaves = gridDim.x * (blockDim.x >> 6);

    for (int g = wave; g < E4; g += totalWaves) {
        const int4 tv = et4[g];                 // types for rows 4g..4g+3
        const size_t r0 = (size_t)g * 4;
        f32x4 v0 = ys[tv.x * 64 + lane];
        f32x4 v1 = ys[tv.y * 64 + lane];
        f32x4 v2 = ys[tv.z * 64 + lane];
        f32x4 v3 = ys[tv.w * 64 + lane];
        __builtin_nontemporal_store(v0, &out4[(r0 + 0) * 64 + lane]);
        __builtin_nontemporal_store(v1, &out4[(r0 + 1) * 64 + lane]);
        __builtin_nontemporal_store(v2, &out4[(r0 + 2) * 64 + lane]);
        __builtin_nontemporal_store(v3, &out4[(r0 + 3) * 64 + lane]);
    }
}

extern "C" void kernel_launch(void* const* d_in, const int* in_sizes, int n_in,
                              void* d_out, int out_size, void* d_ws, size_t ws_size,
                              hipStream_t stream) {
    const float* x_j  = (const float*)d_in[0];   // [E, IN] (first T rows used)
    const float* W    = (const float*)d_in[1];   // [T, IN, OUT]
    const int*   et   = (const int*)d_in[2];     // [E]
    float*       out  = (float*)d_out;           // [E, OUT]

    const int E  = in_sizes[2];                  // 524288
    const int E4 = E / 4;

    // Workspace: partial [T*NCHUNK*OUT] (128 KB) then y [T*OUT] (16 KB)
    float* partial = (float*)d_ws;
    float* y       = partial + (size_t)RL_T * RL_NCHUNK * RL_OUT;

    rl_partial<<<RL_T * RL_NCHUNK, RL_OUT, 0, stream>>>(x_j, W, partial);
    rl_reduce<<<RL_T, RL_OUT, 0, stream>>>(partial, y);

    rl_gather<<<2048, 256, 0, stream>>>((const int4*)et, (const f32x4*)y,
                                        (f32x4*)out, E4);
}

// Round 5
// 103.409 us; speedup vs baseline: 1.2891x; 1.0594x over previous
//
#include <hip/hip_runtime.h>

// Problem shape: E=524288, IN=256, OUT=256, T=16
//   y[t] = x_j[t] @ W[t]       (tiny compute: 16x256x256, 4 MB of W)
//   out[e] = y[edge_types[e]]  (memory-bound gather: 512 MB fp32 writes)
//
// R4 post-mortem: gather ran ~4.9 TB/s vs 6.8 TB/s pure-write fill rate.
// Residual theory: per-iteration et reads interleaved into the write stream
// (HBM read/write turnaround + dependent chain). R5: one contiguous 64-row
// (64 KB) span per wave; all 64 edge types fetched in ONE coalesced 256 B
// burst into LDS at span start; steady state is a pure store stream.

#define RL_IN  256
#define RL_OUT 256
#define RL_T   16

typedef float f32x4 __attribute__((ext_vector_type(4)));

// ---------------------------------------------------------------------------
// Kernel A (fused): y[t][o] = sum_i x[t][i] * W[t][i][o].
// 16 blocks x 1024 threads; thread (c,o) sums 64 i's; LDS reduce over c.
// ---------------------------------------------------------------------------
__global__ __launch_bounds__(1024)
void rl_compute_y(const float* __restrict__ x,
                  const float* __restrict__ W,
                  float* __restrict__ y) {
    const int t = blockIdx.x;            // 0..15
    const int c = threadIdx.x >> 8;      // 0..3
    const int o = threadIdx.x & 255;     // 0..255
    const int i0 = c * 64;

    __shared__ float xs[RL_IN];
    if (threadIdx.x < RL_IN) xs[threadIdx.x] = x[t * RL_IN + threadIdx.x];
    __syncthreads();

    const float* Wt = W + (size_t)t * RL_IN * RL_OUT + (size_t)i0 * RL_OUT;
    float acc = 0.0f;
#pragma unroll 8
    for (int i = 0; i < 64; ++i) {
        acc += xs[i0 + i] * Wt[i * RL_OUT + o];
    }

    __shared__ float part[4][RL_OUT];
    part[c][o] = acc;
    __syncthreads();
    if (c == 0) {
        y[t * RL_OUT + o] = part[0][o] + part[1][o] + part[2][o] + part[3][o];
    }
}

// ---------------------------------------------------------------------------
// Kernel B: gather. One wave owns a contiguous 64-row (64 KB) span.
// Prologue: one coalesced 256 B et burst -> LDS. Steady state: 64 independent
// 1 KB nontemporal stores, type lookup = wave-uniform LDS broadcast.
// ---------------------------------------------------------------------------
__global__ __launch_bounds__(256)
void rl_gather(const int* __restrict__ et,    // [E]
               const f32x4* __restrict__ y4,  // [T*64]
               f32x4* __restrict__ out4,      // [E*64]
               int E) {
    __shared__ f32x4 ys[RL_T * (RL_OUT / 4)];  // 1024 * 16B = 16 KB
    __shared__ int tys[256];                   // per-thread type slot

    for (int i = threadIdx.x; i < RL_T * (RL_OUT / 4); i += blockDim.x)
        ys[i] = y4[i];
    __syncthreads();

    const int lane       = threadIdx.x & 63;
    const int waveBase   = threadIdx.x & ~63;   // LDS base for this wave's types
    const int wave       = blockIdx.x * (blockDim.x >> 6) + (threadIdx.x >> 6);
    const int totalWaves = gridDim.x * (blockDim.x >> 6);

    for (int base = wave * 64; base < E; base += totalWaves * 64) {
        // one coalesced 256 B read per wave; parked in LDS (same-wave use,
        // no barrier needed -- compiler inserts lgkmcnt waits)
        tys[waveBase + lane] = et[base + lane];

        if (base + 64 <= E) {
#pragma unroll 8
            for (int r = 0; r < 64; ++r) {
                const int t = tys[waveBase + r];        // uniform broadcast
                f32x4 v = ys[t * 64 + lane];
                __builtin_nontemporal_store(
                    v, &out4[(size_t)(base + r) * 64 + lane]);
            }
        } else {
            for (int r = 0; base + r < E; ++r) {
                const int t = tys[waveBase + r];
                f32x4 v = ys[t * 64 + lane];
                __builtin_nontemporal_store(
                    v, &out4[(size_t)(base + r) * 64 + lane]);
            }
        }
    }
}

extern "C" void kernel_launch(void* const* d_in, const int* in_sizes, int n_in,
                              void* d_out, int out_size, void* d_ws, size_t ws_size,
                              hipStream_t stream) {
    const float* x_j  = (const float*)d_in[0];   // [E, IN] (first T rows used)
    const float* W    = (const float*)d_in[1];   // [T, IN, OUT]
    const int*   et   = (const int*)d_in[2];     // [E]
    float*       out  = (float*)d_out;           // [E, OUT]

    const int E = in_sizes[2];                   // 524288

    float* y = (float*)d_ws;                     // [T, OUT] = 16 KB scratch

    rl_compute_y<<<RL_T, 1024, 0, stream>>>(x_j, W, y);

    // 2048 blocks x 4 waves = 8192 waves x 64 rows = 524288 rows (one span
    // each at E=524288; grid-stride loop keeps it generic).
    rl_gather<<<2048, 256, 0, stream>>>(et, (const f32x4*)y,
                                        (f32x4*)out, E);
}